// Round 13
// baseline (297.477 us; speedup 1.0000x reference)
//
#include <hip/hip_runtime.h>
#include <cstdint>
#include <cstddef>

typedef int int4v __attribute__((ext_vector_type(4)));
typedef signed char schar;

#define DEVI __device__ __forceinline__

DEVI void load_lds16(const void* g, void* l) {
  __builtin_amdgcn_global_load_lds(
      (const __attribute__((address_space(1))) void*)g,
      (__attribute__((address_space(3))) void*)l, 16, 0, 0);
}

// Bare advisory waits — no sched_barrier, no memory clobber.
#define BAR() __builtin_amdgcn_s_barrier()
#define LGKM(n) asm volatile("s_waitcnt lgkmcnt(" #n ")")
#define VMW(n) asm volatile("s_waitcnt vmcnt(" #n ")")

// ---- pack int32 -> int8, linear (4 elems/thread) ----
__global__ __launch_bounds__(256) void pack_i8(const int* __restrict__ src,
                                               signed char* __restrict__ dst,
                                               int n4) {
  int i = blockIdx.x * 256 + threadIdx.x;
  if (i >= n4) return;
  int4v v = ((const int4v*)src)[i];
  int p = (v.x & 255) | ((v.y & 255) << 8) | ((v.z & 255) << 16) | (v.w << 24);
  ((int*)dst)[i] = p;
}

// ---- pack + transpose: w[K][N] int32 -> wT[N][K] int8, 64x64 LDS tiles ----
__global__ __launch_bounds__(256) void pack_wT(const int* __restrict__ w,
                                               signed char* __restrict__ wT,
                                               int K, int N) {
  __shared__ signed char t[64][68];
  int n0 = blockIdx.x * 64, k0 = blockIdx.y * 64;
  int tr = threadIdx.x >> 6, tc = threadIdx.x & 63;
#pragma unroll
  for (int i = 0; i < 16; ++i) {
    int r = i * 4 + tr;
    t[r][tc] = (signed char)w[(size_t)(k0 + r) * N + n0 + tc];
  }
  __syncthreads();
#pragma unroll
  for (int i = 0; i < 16; ++i) {
    int r = i * 4 + tr;
    wT[(size_t)(n0 + r) * K + k0 + tc] = t[tc][r];
  }
}

// ---- 256x256 i8 GEMM, A via LDS + B DIRECT-TO-REG (prefetched) ----
// 8 waves (2Mx4N), 128x64 out/wave, acc[8][4]=128 AGPR.
// BK=128 B (2 K-steps). A: LDS-staged 2 tiles ahead, 4 bufs x 32 KB.
// B: 4 MB L2-resident panel read straight to VGPR — kk0-half prefetched
// ONE TILE ahead, kk1-half issued at tile top (half-tile slack). Cuts
// per-tile CU LDS reads 192->128 b128 and halves staging writes (i8's
// 2xK MFMA is too short to hide the full bf16-template LDS stream; the
// stream itself must shrink — R2-R12 established schedule-invariance).
// vmcnt(8) at tile end is reorder-robust: >=4 of this tile's 12 VMEM
// retired => ALL prior-tile loads retired (incl. A-stage needed at the
// barrier). vmcnt never 0 in steady state.
template <int EPI>
__global__ __launch_bounds__(512, 2) void gemmB(
    const schar* __restrict__ A, const schar* __restrict__ BT,
    int M, int N, int K, const int* __restrict__ bias_i,
    const float* __restrict__ alphaP, const float* __restrict__ betaP,
    const float* __restrict__ bias_f, schar* __restrict__ outQ,
    float* __restrict__ outF) {
  extern __shared__ schar lds[];

  const int tid = threadIdx.x;
  const int wid = tid >> 6, lane = tid & 63;
  const int wr = wid >> 2, wc = wid & 3;  // 2M x 4N waves, 128x64 each
  const int l16 = lane & 15, l4 = lane >> 4;

  // XCD-bijective block swizzle (nwg % 8 == 0 for both GEMMs)
  const int gx = gridDim.x;
  const int nwg = gx * gridDim.y;
  const int bid = blockIdx.y * gx + blockIdx.x;
  const int swz = (bid & 7) * (nwg >> 3) + (bid >> 3);
  const int rowBase = (swz / gx) * 256;
  const int colBase = (swz % gx) * 256;
  const int NT = K >> 7;  // 128-B K-tiles (even: 8 or 32)

  const float alpha = alphaP[0];
  const float beta = (EPI == 0) ? betaP[0] : 0.f;
  asm volatile("" ::"s"(alpha), "s"(beta));
  LGKM(0);

  // A staging (pre-swizzled global slot; LDS dest linear). 4 rounds/thread.
  const schar* gA[4];
#pragma unroll
  for (int c = 0; c < 4; ++c) {
    int o = c * 8192 + tid * 16;
    int r = o >> 7;  // row 0..255 (128-B rows)
    int g = ((o >> 4) & 7) ^ (r & 7);
    gA[c] = A + (size_t)(rowBase + r) * K + g * 16;
  }
  auto stageA = [&](int buf, int t) {
    schar* d = lds + buf * 32768 + wid * 1024;
#pragma unroll
    for (int c = 0; c < 4; ++c)
      load_lds16(gA[c] + (size_t)t * 128, d + c * 8192);
  };

  // B direct: lane reads BT[col][T*128 + kk*64 + l4*16 .. +15]
  const schar* gBp[4];
#pragma unroll
  for (int ni = 0; ni < 4; ++ni)
    gBp[ni] = BT + (size_t)(colBase + wc * 64 + ni * 16 + l16) * K + l4 * 16;

  // A fragment reads: row = wr*128 + f*16 + l16; slot lane-const per kk
  const int so0 = ((0 + l4) ^ (l16 & 7)) * 16;
  const int so1 = ((4 + l4) ^ (l16 & 7)) * 16;
  const int abase = (wr * 128 + l16) * 128;  // + f*2048 + so

  int4v acc[8][4] = {};
  int4v aF[4], bk1[4];
  int4v bA[4], bB[4];  // kk0-half of B, double-buffered by tile

#define LOADB(DST, T, KOFF)                                         \
  _Pragma("unroll") for (int ni = 0; ni < 4; ++ni) (DST)[ni] =      \
      *(const int4v*)(gBp[ni] + (size_t)(T)*128 + (KOFF))
#define RDA4(G, SO, Ab)                                             \
  _Pragma("unroll") for (int m = 0; m < 4; ++m) aF[m] =             \
      *(const int4v*)((Ab) + abase + ((G)*4 + m) * 2048 + (SO))
#define MM16(G, BF)                                                    \
  do {                                                                 \
    __builtin_amdgcn_s_setprio(1);                                     \
    _Pragma("unroll") for (int m = 0; m < 4; ++m)                      \
        _Pragma("unroll") for (int ni = 0; ni < 4; ++ni)               \
            acc[(G)*4 + m][ni] = __builtin_amdgcn_mfma_i32_16x16x64_i8(\
                aF[m], (BF)[ni], acc[(G)*4 + m][ni], 0, 0, 0);         \
    __builtin_amdgcn_s_setprio(0);                                     \
  } while (0)

  // One tile: CUR = this tile's kk0 B-frags, NXT = next tile's (prefetch)
#define TILE(T, CUR, NXT)                                           \
  do {                                                              \
    const schar* Ab = lds + ((T)&3) * 32768;                        \
    if ((T) + 2 < NT) stageA(((T) + 2) & 3, (T) + 2);               \
    LOADB(bk1, (T), 64);            /* kk1, half-tile slack */      \
    if ((T) + 1 < NT) LOADB(NXT, (T) + 1, 0); /* kk0 prefetch */    \
    RDA4(0, so0, Ab);                                               \
    MM16(0, CUR);                                                   \
    RDA4(1, so0, Ab);                                               \
    MM16(1, CUR);                                                   \
    RDA4(0, so1, Ab);                                               \
    MM16(0, bk1);                                                   \
    RDA4(1, so1, Ab);                                               \
    MM16(1, bk1);                                                   \
    if ((T) + 2 < NT) VMW(8);                                       \
    BAR();                                                          \
  } while (0)

  // prologue: stage A tiles 0,1; prefetch B(0) kk0; full drain once
  stageA(0, 0);
  stageA(1, 1);
  LOADB(bA, 0, 0);
  VMW(0);
  BAR();

  for (int T = 0; T < NT; T += 2) {
    TILE(T, bA, bB);
    TILE(T + 1, bB, bA);
  }

  // ---- epilogue; C/D frag: col = lane&15, row = (lane>>4)*4 + j ----
  if (EPI == 0) {
#pragma unroll
    for (int MI = 0; MI < 8; ++MI) {
      int row = rowBase + wr * 128 + MI * 16 + l4 * 4;
#pragma unroll
      for (int NI = 0; NI < 4; ++NI) {
        int col = colBase + wc * 64 + NI * 16 + l16;
        float bt = (float)bias_i[col] * beta;
#pragma unroll
        for (int j = 0; j < 4; ++j) {
          float h = (float)acc[MI][NI][j] * alpha + bt;
          h = fmaxf(h, 0.f);
          h = rintf(h);  // numpy round-half-even
          h = fminf(h, 127.f);
          outQ[(size_t)(row + j) * N + col] = (schar)h;
        }
      }
    }
  } else {
#pragma unroll
    for (int MI = 0; MI < 8; ++MI) {
      int row = rowBase + wr * 128 + MI * 16 + l4 * 4;
#pragma unroll
      for (int NI = 0; NI < 4; ++NI) {
        int col = colBase + wc * 64 + NI * 16 + l16;
        float bv = bias_f[col];
#pragma unroll
        for (int j = 0; j < 4; ++j)
          outF[(size_t)(row + j) * N + col] =
              (float)acc[MI][NI][j] * alpha + bv;
      }
    }
  }
#undef LOADB
#undef RDA4
#undef MM16
#undef TILE
}

extern "C" void kernel_launch(void* const* d_in, const int* in_sizes, int n_in,
                              void* d_out, int out_size, void* d_ws,
                              size_t ws_size, hipStream_t stream) {
  const int M = 16384, H = 1024, I = 4096;  // B*S = 16384
  const int* hidden = (const int*)d_in[0];
  const int* w_fc = (const int*)d_in[1];
  const int* b_fc = (const int*)d_in[2];
  const float* alpha_fc = (const float*)d_in[3];
  const float* beta_fc = (const float*)d_in[4];
  const int* w_proj = (const int*)d_in[5];
  const float* b_proj = (const float*)d_in[6];
  const float* alpha_proj = (const float*)d_in[7];
  float* out = (float*)d_out;

  signed char* hq = (signed char*)d_ws;     // [M][I]  64 MB
  signed char* aP = hq + (size_t)M * I;     // [M][H]  16 MB
  signed char* wfcT = aP + (size_t)M * H;   // [I][H]   4 MB (w_fc^T)
  signed char* wpT = wfcT + (size_t)I * H;  // [H][I]   4 MB (w_proj^T)

  hipFuncSetAttribute((const void*)gemmB<0>,
                      hipFuncAttributeMaxDynamicSharedMemorySize, 131072);
  hipFuncSetAttribute((const void*)gemmB<1>,
                      hipFuncAttributeMaxDynamicSharedMemorySize, 131072);

  pack_i8<<<(M * H / 4 + 255) / 256, 256, 0, stream>>>(hidden, aP, M * H / 4);
  pack_wT<<<dim3(I / 64, H / 64), 256, 0, stream>>>(w_fc, wfcT, H, I);
  pack_wT<<<dim3(H / 64, I / 64), 256, 0, stream>>>(w_proj, wpT, I, H);

  gemmB<0><<<dim3(I / 256, M / 256), 512, 131072, stream>>>(
      aP, wfcT, M, I, H, b_fc, alpha_fc, beta_fc, nullptr, hq, nullptr);
  gemmB<1><<<dim3(H / 256, M / 256), 512, 131072, stream>>>(
      hq, wpT, M, H, I, nullptr, alpha_proj, nullptr, b_proj, nullptr, out);
}

// Round 14
// 177.597 us; speedup vs baseline: 1.6750x; 1.6750x over previous
//
#include <hip/hip_runtime.h>
#include <cstdint>
#include <cstddef>

typedef int int4v __attribute__((ext_vector_type(4)));
typedef signed char schar;

#define DEVI __device__ __forceinline__

DEVI void load_lds16(const void* g, void* l) {
  __builtin_amdgcn_global_load_lds(
      (const __attribute__((address_space(1))) void*)g,
      (__attribute__((address_space(3))) void*)l, 16, 0, 0);
}

// Bare advisory waits — no sched_barrier, no memory clobber.
#define BAR() __builtin_amdgcn_s_barrier()
#define LGKM(n) asm volatile("s_waitcnt lgkmcnt(" #n ")")
#define VMW(n) asm volatile("s_waitcnt vmcnt(" #n ")")

// ---- pack int32 -> int8, linear (4 elems/thread) ----
__global__ __launch_bounds__(256) void pack_i8(const int* __restrict__ src,
                                               signed char* __restrict__ dst,
                                               int n4) {
  int i = blockIdx.x * 256 + threadIdx.x;
  if (i >= n4) return;
  int4v v = ((const int4v*)src)[i];
  int p = (v.x & 255) | ((v.y & 255) << 8) | ((v.z & 255) << 16) | (v.w << 24);
  ((int*)dst)[i] = p;
}

// ---- pack + transpose: w[K][N] int32 -> wT[N][K] int8, 64x64 LDS tiles ----
__global__ __launch_bounds__(256) void pack_wT(const int* __restrict__ w,
                                               signed char* __restrict__ wT,
                                               int K, int N) {
  __shared__ signed char t[64][68];
  int n0 = blockIdx.x * 64, k0 = blockIdx.y * 64;
  int tr = threadIdx.x >> 6, tc = threadIdx.x & 63;
#pragma unroll
  for (int i = 0; i < 16; ++i) {
    int r = i * 4 + tr;
    t[r][tc] = (signed char)w[(size_t)(k0 + r) * N + n0 + tc];
  }
  __syncthreads();
#pragma unroll
  for (int i = 0; i < 16; ++i) {
    int r = i * 4 + tr;
    wT[(size_t)(n0 + r) * K + k0 + tc] = t[tc][r];
  }
}

// ---- 256x256 16-wave i8 GEMM, BARRIER PER 2 TILES (drift window) ----
// 16 waves (4Mx4N), 64x64/wave, acc[4][4]=64 AGPR, ~124 regs -> 4 w/SIMD.
// BK=64 B/tile; FOUR buffers x 32 KB (A 16K + B 16K each) = 128 KiB.
// ONE barrier + one vmcnt(0) + one lgkm(0) per TWO tiles: within the
// window, waves free-run (reads(T), MFMA(T), reads(T+1), MFMA(T+1) with
// only compiler-counted waits). Port-service skew desynchronizes the 4
// waves/SIMD, so one wave's MFMA overlaps another's reads — the per-tile
// barrier in R5-R11 re-aligned all waves every tile and forced the
// read-burst/MFMA-burst convoy (port idle during MFMA, unit idle during
// reads; measured 6600 cy/tile = exact serial sum).
// WAR: window [T,T+1] reads bufs T&3,(T+1)&3, stages (T+2)&3,(T+3)&3 —
// all distinct; lgkm(0) pre-barrier drains reads before buf(T&3) is
// re-staged next window. vmcnt(0) retires staging issued a window ago.
template <int EPI>
__global__ __launch_bounds__(1024, 4) void gemmV(
    const schar* __restrict__ A, const schar* __restrict__ BT,
    int M, int N, int K, const int* __restrict__ bias_i,
    const float* __restrict__ alphaP, const float* __restrict__ betaP,
    const float* __restrict__ bias_f, schar* __restrict__ outQ,
    float* __restrict__ outF) {
  extern __shared__ schar lds[];

  const int tid = threadIdx.x;
  const int wid = tid >> 6, lane = tid & 63;
  const int wr = wid >> 2, wc = wid & 3;  // 4M x 4N waves, 64x64 each
  const int l16 = lane & 15, l4 = lane >> 4;

  // XCD-bijective block swizzle (nwg % 8 == 0 for both GEMMs)
  const int gx = gridDim.x;
  const int nwg = gx * gridDim.y;
  const int bid = blockIdx.y * gx + blockIdx.x;
  const int swz = (bid & 7) * (nwg >> 3) + (bid >> 3);
  const int rowBase = (swz / gx) * 256;
  const int colBase = (swz % gx) * 256;
  const int NT = K >> 6;  // 64-B K-tiles (16 or 64: even)

  const float alpha = alphaP[0];
  const float beta = (EPI == 0) ? betaP[0] : 0.f;
  asm volatile("" ::"s"(alpha), "s"(beta));
  LGKM(0);

  // staging: 1024 threads cover each 16 KB half in ONE instr.
  // pre-swizzled source (4 slots of 16 B per 64-B row): g = s ^ ((r>>1)&3)
  const int o = tid * 16;
  const int rr = o >> 6;  // row 0..255
  const int gsl = ((o >> 4) & 3) ^ ((rr >> 1) & 3);
  const schar* gAs = A + (size_t)(rowBase + rr) * K + gsl * 16;
  const schar* gBs = BT + (size_t)(colBase + rr) * K + gsl * 16;

  auto stage = [&](int buf, int t) {
    schar* d = lds + buf * 32768 + wid * 1024;
    load_lds16(gAs + (size_t)t * 64, d);            // A half
    load_lds16(gBs + (size_t)t * 64, d + 16384);    // B half
  };

  // fragment reads: slot = l4 ^ ((l16>>1)&3), lane-const (row base %16==0)
  const int slotc = (l4 ^ ((l16 >> 1) & 3)) * 16 + l16 * 64;
  const int aoff = wr * 4096 + slotc;           // + mi*1024
  const int boff = 16384 + wc * 4096 + slotc;   // + ni*1024

  int4v acc[4][4] = {};
  int4v aF[4], bF[4];

#define RDT(Bu)                                                    \
  do {                                                             \
    _Pragma("unroll") for (int mi = 0; mi < 4; ++mi) aF[mi] =      \
        *(const int4v*)((Bu) + aoff + mi * 1024);                  \
    _Pragma("unroll") for (int ni = 0; ni < 4; ++ni) bF[ni] =      \
        *(const int4v*)((Bu) + boff + ni * 1024);                  \
  } while (0)
#define MMT()                                                          \
  do {                                                                 \
    __builtin_amdgcn_s_setprio(1);                                     \
    _Pragma("unroll") for (int mi = 0; mi < 4; ++mi)                   \
        _Pragma("unroll") for (int ni = 0; ni < 4; ++ni) acc[mi][ni] = \
        __builtin_amdgcn_mfma_i32_16x16x64_i8(aF[mi], bF[ni],          \
                                              acc[mi][ni], 0, 0, 0);   \
    __builtin_amdgcn_s_setprio(0);                                     \
  } while (0)

  // prologue: stage tiles 0,1; drain; barrier
  stage(0, 0);
  stage(1, 1);
  VMW(0);
  BAR();

  for (int T = 0; T < NT; T += 2) {
    // stage next window's tiles into the two free buffers
    if (T + 2 < NT) stage((T + 2) & 3, T + 2);
    if (T + 3 < NT) stage((T + 3) & 3, T + 3);

    // two tiles, no internal sync: waves drift; compiler-counted waits
    RDT(lds + (T & 3) * 32768);
    MMT();
    RDT(lds + ((T + 1) & 3) * 32768);
    MMT();

    LGKM(0);  // window reads drained (WAR vs next window's staging)
    VMW(0);   // staging landed (issued a full window earlier)
    BAR();
  }

  // ---- epilogue; C/D frag: col = lane&15, row = (lane>>4)*4 + j ----
  if (EPI == 0) {
#pragma unroll
    for (int MI = 0; MI < 4; ++MI) {
      int row = rowBase + wr * 64 + MI * 16 + l4 * 4;
#pragma unroll
      for (int NI = 0; NI < 4; ++NI) {
        int col = colBase + wc * 64 + NI * 16 + l16;
        float bt = (float)bias_i[col] * beta;
#pragma unroll
        for (int j = 0; j < 4; ++j) {
          float h = (float)acc[MI][NI][j] * alpha + bt;
          h = fmaxf(h, 0.f);
          h = rintf(h);  // numpy round-half-even
          h = fminf(h, 127.f);
          outQ[(size_t)(row + j) * N + col] = (schar)h;
        }
      }
    }
  } else {
#pragma unroll
    for (int MI = 0; MI < 4; ++MI) {
      int row = rowBase + wr * 64 + MI * 16 + l4 * 4;
#pragma unroll
      for (int NI = 0; NI < 4; ++NI) {
        int col = colBase + wc * 64 + NI * 16 + l16;
        float bv = bias_f[col];
#pragma unroll
        for (int j = 0; j < 4; ++j)
          outF[(size_t)(row + j) * N + col] =
              (float)acc[MI][NI][j] * alpha + bv;
      }
    }
  }
#undef RDT
#undef MMT
}

extern "C" void kernel_launch(void* const* d_in, const int* in_sizes, int n_in,
                              void* d_out, int out_size, void* d_ws,
                              size_t ws_size, hipStream_t stream) {
  const int M = 16384, H = 1024, I = 4096;  // B*S = 16384
  const int* hidden = (const int*)d_in[0];
  const int* w_fc = (const int*)d_in[1];
  const int* b_fc = (const int*)d_in[2];
  const float* alpha_fc = (const float*)d_in[3];
  const float* beta_fc = (const float*)d_in[4];
  const int* w_proj = (const int*)d_in[5];
  const float* b_proj = (const float*)d_in[6];
  const float* alpha_proj = (const float*)d_in[7];
  float* out = (float*)d_out;

  signed char* hq = (signed char*)d_ws;     // [M][I]  64 MB
  signed char* aP = hq + (size_t)M * I;     // [M][H]  16 MB
  signed char* wfcT = aP + (size_t)M * H;   // [I][H]   4 MB (w_fc^T)
  signed char* wpT = wfcT + (size_t)I * H;  // [H][I]   4 MB (w_proj^T)

  hipFuncSetAttribute((const void*)gemmV<0>,
                      hipFuncAttributeMaxDynamicSharedMemorySize, 131072);
  hipFuncSetAttribute((const void*)gemmV<1>,
                      hipFuncAttributeMaxDynamicSharedMemorySize, 131072);

  pack_i8<<<(M * H / 4 + 255) / 256, 256, 0, stream>>>(hidden, aP, M * H / 4);
  pack_wT<<<dim3(I / 64, H / 64), 256, 0, stream>>>(w_fc, wfcT, H, I);
  pack_wT<<<dim3(H / 64, I / 64), 256, 0, stream>>>(w_proj, wpT, I, H);

  gemmV<0><<<dim3(I / 256, M / 256), 1024, 131072, stream>>>(
      aP, wfcT, M, I, H, b_fc, alpha_fc, beta_fc, nullptr, hq, nullptr);
  gemmV<1><<<dim3(H / 256, M / 256), 1024, 131072, stream>>>(
      hq, wpT, M, H, I, nullptr, alpha_proj, nullptr, b_proj, nullptr, out);
}